// Round 4
// baseline (109058.862 us; speedup 1.0000x reference)
//
#include <hip/hip_runtime.h>
#include <math.h>

#define T_DIM 512
#define B_DIM 64
#define I_DIM 1024
#define H_DIM 1024

// d_out layout (flat f32): ys [T][B][2H], hT_f [B][H], cT_f, hT_b, cT_b
#define OUT_HTF (T_DIM * B_DIM * 2 * H_DIM)
#define OUT_CTF (OUT_HTF + B_DIM * H_DIM)
#define OUT_HTB (OUT_CTF + B_DIM * H_DIM)
#define OUT_CTB (OUT_HTB + B_DIM * H_DIM)

__device__ __forceinline__ float sigmoidf_(float v) {
    return 1.0f / (1.0f + expf(-v));
}

// Persistent bidirectional LSTM.
// Grid: 256 blocks x 256 threads, exactly 1 block/CU (160 KB LDS forces it).
// Block bid: dir = bid>>7, u0 = (bid&127)*8  -> owns 32 gate-rows {i,f,g,o}x8u.
// LDS: W_hh slice [32][1024] f32 = 128 KB resident + 2x[64][64] staging = 32 KB.
// Per step: gates = accx (x-part, computed LAST step) + h_prev @ W_hh(LDS)^T;
// while doing the h-GEMM, also accumulate accxn = x_{t+1} @ W_ih^T (streamed W).
// c-state lives in 2 registers/thread. Grid barrier (2-level atomic) per step.
__global__ __launch_bounds__(256, 1) void lstm_persist(
    const float* __restrict__ x,
    const float* __restrict__ h0f, const float* __restrict__ c0f,
    const float* __restrict__ h0b, const float* __restrict__ c0b,
    const float* __restrict__ wihf, const float* __restrict__ whhf,
    const float* __restrict__ bihf, const float* __restrict__ bhhf,
    const float* __restrict__ wihb, const float* __restrict__ whhb,
    const float* __restrict__ bihb, const float* __restrict__ bhhb,
    float* __restrict__ out, int* __restrict__ bar)
{
    __shared__ float smem[32768 + 8192];   // 160 KB exactly
    float* Wl    = smem;                   // [32 rows][1024 k]
    float* stage = smem + 32768;           // 2 x [64 m][64 k], float4-swizzled

    const int tid  = threadIdx.x;
    const int bid  = blockIdx.x;
    const int dir  = bid >> 7;
    const int u0   = (bid & 127) * 8;
    const int lane = tid & 63;             // batch row m in the GEMM
    const int g    = tid >> 6;             // gate 0..3 (i,f,g,o)

    const float* wih = dir ? wihb : wihf;
    const float* whh = dir ? whhb : whhf;
    const float* bih = dir ? bihb : bihf;
    const float* bhh = dir ? bhhb : bhhf;

    // ---- preload W_hh slice into LDS (once): local row r=g'*8+ci ----
#pragma unroll 4
    for (int r = 0; r < 32; ++r) {
        const int grow = (r >> 3) * H_DIM + u0 + (r & 7);
        *reinterpret_cast<float4*>(&Wl[r * 1024 + tid * 4]) =
            *reinterpret_cast<const float4*>(whh + (size_t)grow * 1024 + tid * 4);
    }
    __syncthreads();

    const int row0 = g * H_DIM + u0;
    float bias[8];
#pragma unroll
    for (int ci = 0; ci < 8; ++ci) bias[ci] = bih[row0 + ci] + bhh[row0 + ci];

    // ---- persistent c-state: cells (cm, cu) and (cm+32, cu) ----
    const int cu = tid & 7;
    const int cm = tid >> 3;               // 0..31
    const float* cinit = dir ? c0b : c0f;
    float creg[2];
    creg[0] = cinit[(size_t)cm * H_DIM + u0 + cu];
    creg[1] = cinit[(size_t)(cm + 32) * H_DIM + u0 + cu];

    float4 ld[4];                          // staging regs

    auto issue_stage = [&](const float* src, int stride, int kb) {
#pragma unroll
        for (int p = 0; p < 4; ++p) {
            const int e = p * 256 + tid;   // float4 slot 0..1023
            const int m = e >> 4, q = e & 15;
            ld[p] = *reinterpret_cast<const float4*>(
                src + (size_t)m * stride + kb + q * 4);
        }
    };
    auto write_stage = [&](int buf) {
        float* dst = stage + buf * 4096;
#pragma unroll
        for (int p = 0; p < 4; ++p) {
            const int e = p * 256 + tid;
            const int m = e >> 4, q = e & 15;
            *reinterpret_cast<float4*>(&dst[m * 64 + (q ^ (m & 15)) * 4]) = ld[p];
        }
    };
    auto compute_h = [&](int kb, int buf, float* acc) {
        const float* sb = stage + buf * 4096 + lane * 64;
        const int msw = lane & 15;
#pragma unroll 4
        for (int q = 0; q < 16; ++q) {
            const float4 a = *reinterpret_cast<const float4*>(&sb[(q ^ msw) * 4]);
#pragma unroll
            for (int ci = 0; ci < 8; ++ci) {
                const float4 wv = *reinterpret_cast<const float4*>(
                    &Wl[(g * 8 + ci) * 1024 + kb + q * 4]);   // LDS broadcast
                acc[ci] = fmaf(a.x, wv.x, fmaf(a.y, wv.y,
                          fmaf(a.z, wv.z, fmaf(a.w, wv.w, acc[ci]))));
            }
        }
    };
    auto compute_x = [&](int kb, int buf, float* acc) {
        const float* sb = stage + buf * 4096 + lane * 64;
        const float* wb = wih + (size_t)row0 * 1024 + kb;
        const int msw = lane & 15;
#pragma unroll 4
        for (int q = 0; q < 16; ++q) {
            const float4 a = *reinterpret_cast<const float4*>(&sb[(q ^ msw) * 4]);
#pragma unroll
            for (int ci = 0; ci < 8; ++ci) {
                const float4 wv = *reinterpret_cast<const float4*>(
                    wb + (size_t)ci * 1024 + q * 4);          // wave-broadcast
                acc[ci] = fmaf(a.x, wv.x, fmaf(a.y, wv.y,
                          fmaf(a.z, wv.z, fmaf(a.w, wv.w, acc[ci]))));
            }
        }
    };

    // ---- prologue: accx = x_{t0} @ W_ih^T + bias ----
    float accx[8];
#pragma unroll
    for (int ci = 0; ci < 8; ++ci) accx[ci] = bias[ci];
    {
        const int t0 = dir ? (T_DIM - 1) : 0;
        const float* xs = x + (size_t)t0 * B_DIM * I_DIM;
        issue_stage(xs, I_DIM, 0);
        write_stage(0);
        __syncthreads();
        for (int c = 0; c < 16; ++c) {
            if (c < 15) issue_stage(xs, I_DIM, (c + 1) * 64);
            compute_x(c * 64, c & 1, accx);
            if (c < 15) write_stage((c + 1) & 1);
            __syncthreads();
        }
    }

    // ---- main recurrence ----
    for (int s = 0; s < T_DIM; ++s) {
        const int t = dir ? (T_DIM - 1 - s) : s;
        const float* hprev;
        int hst;
        if (s == 0) {
            hprev = dir ? h0b : h0f;
            hst = H_DIM;
        } else {
            const int tp = dir ? (t + 1) : (t - 1);
            hprev = out + (size_t)tp * B_DIM * 2 * H_DIM + dir * H_DIM;
            hst = 2 * H_DIM;
        }
        const bool hasx = (s < T_DIM - 1);
        const int tn = dir ? (t - 1) : (t + 1);
        const float* xn = x + (size_t)(hasx ? tn : t) * B_DIM * I_DIM;
        const int nch = hasx ? 32 : 16;

        float acch[8] = {};
        float accxn[8];
#pragma unroll
        for (int ci = 0; ci < 8; ++ci) accxn[ci] = bias[ci];

        // chunks: c<16 = h (kb=c*64, W from LDS); c>=16 = x_{t+1} (W streamed)
        issue_stage(hprev, hst, 0);
        write_stage(0);
        __syncthreads();
        for (int c = 0; c < nch; ++c) {
            if (c + 1 < nch) {
                if (c + 1 < 16) issue_stage(hprev, hst, (c + 1) * 64);
                else            issue_stage(xn, I_DIM, (c + 1 - 16) * 64);
            }
            if (c < 16) compute_h(c * 64, c & 1, acch);
            else        compute_x((c - 16) * 64, c & 1, accxn);
            if (c + 1 < nch) write_stage((c + 1) & 1);
            __syncthreads();
        }

        // ---- gate exchange in stage area: [g][ci][m], strides 520/65 ----
        float* gsm = stage;
#pragma unroll
        for (int ci = 0; ci < 8; ++ci)
            gsm[g * 520 + ci * 65 + lane] = accx[ci] + acch[ci];
        __syncthreads();

        // ---- cell update: 2 cells/thread, c-state in registers ----
        float hv[2];
#pragma unroll
        for (int k2 = 0; k2 < 2; ++k2) {
            const int m = cm + k2 * 32;
            const float ig = gsm[0 * 520 + cu * 65 + m];
            const float fg = gsm[1 * 520 + cu * 65 + m];
            const float gg = gsm[2 * 520 + cu * 65 + m];
            const float og = gsm[3 * 520 + cu * 65 + m];
            const float cn = sigmoidf_(fg) * creg[k2] + sigmoidf_(ig) * tanhf(gg);
            hv[k2] = sigmoidf_(og) * tanhf(cn);
            creg[k2] = cn;
            out[(size_t)t * B_DIM * 2 * H_DIM + (size_t)m * 2 * H_DIM
                + dir * H_DIM + u0 + cu] = hv[k2];
        }
        if (s == T_DIM - 1) {
            float* hslot = out + (dir ? OUT_HTB : OUT_HTF);
            float* cslot = out + (dir ? OUT_CTB : OUT_CTF);
#pragma unroll
            for (int k2 = 0; k2 < 2; ++k2) {
                const int m = cm + k2 * 32;
                hslot[(size_t)m * H_DIM + u0 + cu] = hv[k2];
                cslot[(size_t)m * H_DIM + u0 + cu] = creg[k2];
            }
        }

        // ---- grid barrier (2-level, device-scope, generation s+1) ----
        __syncthreads();                   // all block writes issued & drained
        if (tid == 0) {
            const int grp = bid >> 5;      // 8 groups of 32 blocks
            __hip_atomic_fetch_add(&bar[grp], 1, __ATOMIC_RELEASE,
                                   __HIP_MEMORY_SCOPE_AGENT);
            if ((bid & 31) == 0) {
                while (__hip_atomic_load(&bar[grp], __ATOMIC_ACQUIRE,
                                         __HIP_MEMORY_SCOPE_AGENT) < 32 * (s + 1))
                    __builtin_amdgcn_s_sleep(2);
                __hip_atomic_fetch_add(&bar[8], 1, __ATOMIC_RELEASE,
                                       __HIP_MEMORY_SCOPE_AGENT);
            }
            while (__hip_atomic_load(&bar[8], __ATOMIC_ACQUIRE,
                                     __HIP_MEMORY_SCOPE_AGENT) < 8 * (s + 1))
                __builtin_amdgcn_s_sleep(2);
        }
        __syncthreads();

#pragma unroll
        for (int ci = 0; ci < 8; ++ci) accx[ci] = accxn[ci];
    }
}

extern "C" void kernel_launch(void* const* d_in, const int* in_sizes, int n_in,
                              void* d_out, int out_size, void* d_ws, size_t ws_size,
                              hipStream_t stream)
{
    const float* x    = (const float*)d_in[0];
    const float* h0f  = (const float*)d_in[1];
    const float* c0f  = (const float*)d_in[2];
    const float* h0b  = (const float*)d_in[3];
    const float* c0b  = (const float*)d_in[4];
    const float* wihf = (const float*)d_in[5];
    const float* whhf = (const float*)d_in[6];
    const float* bihf = (const float*)d_in[7];
    const float* bhhf = (const float*)d_in[8];
    const float* wihb = (const float*)d_in[9];
    const float* whhb = (const float*)d_in[10];
    const float* bihb = (const float*)d_in[11];
    const float* bhhb = (const float*)d_in[12];
    float* out = (float*)d_out;

    // barrier counters (9 ints) — must be zero at each call
    hipMemsetAsync(d_ws, 0, 64, stream);
    lstm_persist<<<dim3(256), dim3(256), 0, stream>>>(
        x, h0f, c0f, h0b, c0b,
        wihf, whhf, bihf, bhhf,
        wihb, whhb, bihb, bhhb,
        out, (int*)d_ws);
}